// Round 1
// baseline (359.025 us; speedup 1.0000x reference)
//
#include <hip/hip_runtime.h>

// ---------------------------------------------------------------------------
// SpatialTransformer: conv1..3 (+relu+pool), BN+dense head -> theta,
// fused nearest-upsample+concat+bilinear-sampler+leaky-relu.
// All fp32. B=16, H=W=256, LOC_C=31.
// ---------------------------------------------------------------------------

#define NEG_SLOPE 0.1f
#define BN_EPS 1e-3f

// K1: conv1 (1->8, 3x3 SAME) + bias + relu + 2x2 maxpool.
// x:(16,256,256,1) -> A:(16,128,128,8). One thread per pooled pixel.
__global__ __launch_bounds__(256) void st_conv1(const float* __restrict__ x,
                                                const float* __restrict__ w,
                                                const float* __restrict__ bias,
                                                float* __restrict__ outA) {
    int idx = blockIdx.x * 256 + threadIdx.x;       // 16*128*128 = 262144
    int px = idx & 127, py = (idx >> 7) & 127, b = idx >> 14;
    const float* xb = x + b * 65536;
    int iy0 = 2 * py - 1, ix0 = 2 * px - 1;
    float p[16];
#pragma unroll
    for (int r = 0; r < 4; ++r) {
        int iy = iy0 + r;
        bool oky = (iy >= 0) && (iy < 256);
#pragma unroll
        for (int cc = 0; cc < 4; ++cc) {
            int ix = ix0 + cc;
            bool ok = oky && (ix >= 0) && (ix < 256);
            p[r * 4 + cc] = ok ? xb[iy * 256 + ix] : 0.0f;
        }
    }
    float m[8];
#pragma unroll
    for (int co = 0; co < 8; ++co) m[co] = -1e30f;
#pragma unroll
    for (int oy = 0; oy < 2; ++oy)
#pragma unroll
        for (int ox = 0; ox < 2; ++ox) {
            float acc[8];
#pragma unroll
            for (int co = 0; co < 8; ++co) acc[co] = 0.0f;
#pragma unroll
            for (int ky = 0; ky < 3; ++ky)
#pragma unroll
                for (int kx = 0; kx < 3; ++kx) {
                    float pv = p[(oy + ky) * 4 + (ox + kx)];
                    const float* wr = w + (ky * 3 + kx) * 8;
#pragma unroll
                    for (int co = 0; co < 8; ++co)
                        acc[co] = fmaf(pv, wr[co], acc[co]);
                }
#pragma unroll
            for (int co = 0; co < 8; ++co) m[co] = fmaxf(m[co], acc[co]);
        }
    float* o = outA + idx * 8;
#pragma unroll
    for (int co = 0; co < 8; ++co) {
        float v = m[co] + bias[co];
        o[co] = v > 0.0f ? v : 0.0f;
    }
}

// K2: conv2 (8->16) + bias + relu + pool. A:(16,128,128,8) -> Bf:(16,64,64,16)
__global__ __launch_bounds__(256) void st_conv2(const float* __restrict__ A,
                                                const float* __restrict__ w,
                                                const float* __restrict__ bias,
                                                float* __restrict__ outB) {
    int idx = blockIdx.x * 256 + threadIdx.x;       // 16*64*64 = 65536
    int px = idx & 63, py = (idx >> 6) & 63, b = idx >> 12;
    const float* Ab = A + b * 128 * 128 * 8;
    int iy0 = 2 * py - 1, ix0 = 2 * px - 1;
    float acc[4][16];
#pragma unroll
    for (int pos = 0; pos < 4; ++pos)
#pragma unroll
        for (int co = 0; co < 16; ++co) acc[pos][co] = 0.0f;

    for (int ci = 0; ci < 8; ++ci) {
        float p[16];
#pragma unroll
        for (int r = 0; r < 4; ++r) {
            int iy = iy0 + r;
            bool oky = (iy >= 0) && (iy < 128);
#pragma unroll
            for (int cc = 0; cc < 4; ++cc) {
                int ix = ix0 + cc;
                bool ok = oky && (ix >= 0) && (ix < 128);
                p[r * 4 + cc] = ok ? Ab[(iy * 128 + ix) * 8 + ci] : 0.0f;
            }
        }
#pragma unroll
        for (int ky = 0; ky < 3; ++ky)
#pragma unroll
            for (int kx = 0; kx < 3; ++kx) {
                const float* wr = w + ((ky * 3 + kx) * 8 + ci) * 16;
                float p00 = p[ky * 4 + kx];
                float p01 = p[ky * 4 + kx + 1];
                float p10 = p[(ky + 1) * 4 + kx];
                float p11 = p[(ky + 1) * 4 + kx + 1];
#pragma unroll
                for (int co = 0; co < 16; ++co) {
                    float wv = wr[co];
                    acc[0][co] = fmaf(p00, wv, acc[0][co]);
                    acc[1][co] = fmaf(p01, wv, acc[1][co]);
                    acc[2][co] = fmaf(p10, wv, acc[2][co]);
                    acc[3][co] = fmaf(p11, wv, acc[3][co]);
                }
            }
    }
    float* o = outB + idx * 16;
#pragma unroll
    for (int co = 0; co < 16; ++co) {
        float m = fmaxf(fmaxf(acc[0][co], acc[1][co]),
                        fmaxf(acc[2][co], acc[3][co]));
        m += bias[co];
        o[co] = m > 0.0f ? m : 0.0f;
    }
}

// K3: conv3 (16->31) + bias + relu (NO pool). Bf:(16,64,64,16) -> C3:(16,64,64,31)
__global__ __launch_bounds__(256) void st_conv3(const float* __restrict__ Bf,
                                                const float* __restrict__ w,
                                                const float* __restrict__ bias,
                                                float* __restrict__ outC) {
    int idx = blockIdx.x * 256 + threadIdx.x;       // 65536
    int ix = idx & 63, iy = (idx >> 6) & 63, b = idx >> 12;
    const float* Bb = Bf + b * 64 * 64 * 16;
    float acc[31];
#pragma unroll
    for (int co = 0; co < 31; ++co) acc[co] = 0.0f;

    for (int ci = 0; ci < 16; ++ci) {
        float p[9];
#pragma unroll
        for (int ky = 0; ky < 3; ++ky) {
            int y = iy + ky - 1;
            bool oky = (y >= 0) && (y < 64);
#pragma unroll
            for (int kx = 0; kx < 3; ++kx) {
                int xx = ix + kx - 1;
                bool ok = oky && (xx >= 0) && (xx < 64);
                p[ky * 3 + kx] = ok ? Bb[(y * 64 + xx) * 16 + ci] : 0.0f;
            }
        }
#pragma unroll
        for (int k = 0; k < 9; ++k) {
            float pv = p[k];
            const float* wr = w + (k * 16 + ci) * 31;
#pragma unroll
            for (int co = 0; co < 31; ++co)
                acc[co] = fmaf(pv, wr[co], acc[co]);
        }
    }
    float* o = outC + idx * 31;
#pragma unroll
    for (int co = 0; co < 31; ++co) {
        float v = acc[co] + bias[co];
        o[co] = v > 0.0f ? v : 0.0f;
    }
}

// K3b: 2x2 maxpool C3 -> xi (16,32,32,31); also emit BN-folded fprime.
__global__ __launch_bounds__(256) void st_pool3(const float* __restrict__ C3,
                                                const float* __restrict__ gamma,
                                                const float* __restrict__ beta,
                                                const float* __restrict__ mean,
                                                const float* __restrict__ var,
                                                float* __restrict__ xi,
                                                float* __restrict__ fprime) {
    int idx = blockIdx.x * 256 + threadIdx.x;       // 16*31744 = 507904
    unsigned j = (unsigned)idx % 31744u;
    unsigned b = (unsigned)idx / 31744u;
    unsigned p2 = j / 31u;
    unsigned co = j - p2 * 31u;
    unsigned px = p2 & 31u, py = p2 >> 5;
    const float* Cb = C3 + b * 64 * 64 * 31;
    float m = -1e30f;
#pragma unroll
    for (int dy = 0; dy < 2; ++dy)
#pragma unroll
        for (int dx = 0; dx < 2; ++dx)
            m = fmaxf(m, Cb[((2 * py + dy) * 64 + (2 * px + dx)) * 31 + co]);
    xi[idx] = m;
    float sc = gamma[j] * rsqrtf(var[j] + BN_EPS);
    fprime[idx] = (m - mean[j]) * sc + beta[j];
}

// K4: split-K GEMM: partial[o][slice][b] = sum_{j in slice} fprime[b,j]*d1_k[j,o]
__global__ __launch_bounds__(256) void st_d1(const float* __restrict__ fp,
                                             const float* __restrict__ k1,
                                             float* __restrict__ partial) {
    int o = blockIdx.x;        // 64
    int slice = blockIdx.y;    // 16
    int t = threadIdx.x;
    float acc[16];
#pragma unroll
    for (int b = 0; b < 16; ++b) acc[b] = 0.0f;
    int jend = (slice + 1) * 1984;
    for (int j = slice * 1984 + t; j < jend; j += 256) {
        float kv = k1[j * 64 + o];
#pragma unroll
        for (int b = 0; b < 16; ++b)
            acc[b] = fmaf(fp[b * 31744 + j], kv, acc[b]);
    }
#pragma unroll
    for (int b = 0; b < 16; ++b) {
        float v = acc[b];
#pragma unroll
        for (int off = 32; off > 0; off >>= 1) v += __shfl_down(v, off, 64);
        acc[b] = v;
    }
    __shared__ float red[4][16];
    int wave = t >> 6, lane = t & 63;
    if (lane == 0) {
#pragma unroll
        for (int b = 0; b < 16; ++b) red[wave][b] = acc[b];
    }
    __syncthreads();
    if (t < 16) {
        float s = red[0][t] + red[1][t] + red[2][t] + red[3][t];
        partial[(o * 16 + slice) * 16 + t] = s;
    }
}

// K4b: reduce slices, add bias, relu -> h1 (16,64)
__global__ __launch_bounds__(256) void st_d1b(const float* __restrict__ partial,
                                              const float* __restrict__ bias,
                                              float* __restrict__ h1) {
    int gid = blockIdx.x * 256 + threadIdx.x;       // 1024
    int o = gid >> 4, b = gid & 15;
    float s = 0.0f;
#pragma unroll
    for (int sl = 0; sl < 16; ++sl) s += partial[(o * 16 + sl) * 16 + b];
    s += bias[o];
    h1[b * 64 + o] = s > 0.0f ? s : 0.0f;
}

// K5: d2 (64->96, relu) then d3 (96->6) -> theta (16,6). One block per batch.
__global__ __launch_bounds__(128) void st_theta(const float* __restrict__ h1,
                                                const float* __restrict__ k2,
                                                const float* __restrict__ b2,
                                                const float* __restrict__ k3,
                                                const float* __restrict__ b3,
                                                float* __restrict__ theta) {
    int b = blockIdx.x, t = threadIdx.x;
    __shared__ float h2[96];
    if (t < 96) {
        float s = b2[t];
        for (int i = 0; i < 64; ++i) s = fmaf(h1[b * 64 + i], k2[i * 96 + t], s);
        h2[t] = s > 0.0f ? s : 0.0f;
    }
    __syncthreads();
    if (t < 6) {
        float s = b3[t];
        for (int i = 0; i < 96; ++i) s = fmaf(h2[i], k3[i * 6 + t], s);
        theta[b * 6 + t] = s;
    }
}

// K6: fused grid-gen + nearest-upsample-concat + bilinear sampler + leaky relu.
// out:(16,256,256,32). Thread = (pixel, channel); c==0 samples x, c>0 samples xi.
__global__ __launch_bounds__(256) void st_sample(const float* __restrict__ x,
                                                 const float* __restrict__ xi,
                                                 const float* __restrict__ theta,
                                                 float* __restrict__ out) {
    int gid = blockIdx.x * 256 + threadIdx.x;       // 33,554,432
    int c = gid & 31;
    int pix = gid >> 5;
    int ow = pix & 255, oh = (pix >> 8) & 255, b = pix >> 16;
    const float* th = theta + b * 6;
    float t0 = th[0], t1 = th[1], t2 = th[2], t3 = th[3], t4 = th[4], t5 = th[5];
    float gx = (float)ow / 255.0f * 2.0f - 1.0f;
    float gy = (float)oh / 255.0f * 2.0f - 1.0f;
    float sx = gx * t0 + gy * t3 + t2;
    float sy = gx * t1 + gy * t4 + t5;
    float xf = 0.5f * ((sx + 1.0f) * 255.0f);
    float yf = 0.5f * ((sy + 1.0f) * 255.0f);
    float x0 = floorf(xf), y0 = floorf(yf);
    float x1 = x0 + 1.0f, y1 = y0 + 1.0f;
    x0 = fminf(fmaxf(x0, 0.0f), 255.0f);
    x1 = fminf(fmaxf(x1, 0.0f), 255.0f);
    y0 = fminf(fmaxf(y0, 0.0f), 255.0f);
    y1 = fminf(fmaxf(y1, 0.0f), 255.0f);
    float wa = (x1 - xf) * (y1 - yf);
    float wb = (x1 - xf) * (yf - y0);
    float wc = (xf - x0) * (y1 - yf);
    float wd = (xf - x0) * (yf - y0);
    int xi0 = (int)x0, xi1 = (int)x1, yi0 = (int)y0, yi1 = (int)y1;
    float Ia, Ib, Ic, Id;
    if (c == 0) {
        const float* xb = x + b * 65536;
        Ia = xb[yi0 * 256 + xi0];
        Ib = xb[yi1 * 256 + xi0];
        Ic = xb[yi0 * 256 + xi1];
        Id = xb[yi1 * 256 + xi1];
    } else {
        const float* lb = xi + b * 31744 + (c - 1);
        Ia = lb[((yi0 >> 3) * 32 + (xi0 >> 3)) * 31];
        Ib = lb[((yi1 >> 3) * 32 + (xi0 >> 3)) * 31];
        Ic = lb[((yi0 >> 3) * 32 + (xi1 >> 3)) * 31];
        Id = lb[((yi1 >> 3) * 32 + (xi1 >> 3)) * 31];
    }
    float v = wa * Ia + wb * Ib + wc * Ic + wd * Id;
    out[gid] = v >= 0.0f ? v : NEG_SLOPE * v;
}

extern "C" void kernel_launch(void* const* d_in, const int* in_sizes, int n_in,
                              void* d_out, int out_size, void* d_ws, size_t ws_size,
                              hipStream_t stream) {
    const float* x     = (const float*)d_in[0];
    const float* c1k   = (const float*)d_in[1];
    const float* c1b   = (const float*)d_in[2];
    const float* c2k   = (const float*)d_in[3];
    const float* c2b   = (const float*)d_in[4];
    const float* c3k   = (const float*)d_in[5];
    const float* c3b   = (const float*)d_in[6];
    const float* gamma = (const float*)d_in[7];
    const float* beta  = (const float*)d_in[8];
    const float* mean  = (const float*)d_in[9];
    const float* var   = (const float*)d_in[10];
    const float* d1k   = (const float*)d_in[11];
    const float* d1b   = (const float*)d_in[12];
    const float* d2k   = (const float*)d_in[13];
    const float* d2b   = (const float*)d_in[14];
    const float* d3k   = (const float*)d_in[15];
    const float* d3b   = (const float*)d_in[16];
    float* out = (float*)d_out;
    float* ws  = (float*)d_ws;

    // Workspace layout (floats). Region reuse: C3 overwrites A (A dead after
    // conv2); xi/fprime overwrite Bf (Bf dead after conv3).
    float* A       = ws;                       // 2,097,152
    float* Bf      = ws + 2097152;             // 1,048,576
    float* C3      = ws;                       // 2,031,616 (reuse A)
    float* xibuf   = ws + 2097152;             //   507,904 (reuse Bf)
    float* fprime  = ws + 2097152 + 507904;    //   507,904
    float* partial = ws + 3145728;             //    16,384
    float* h1      = ws + 3145728 + 16384;     //     1,024
    float* theta   = ws + 3145728 + 17408;     //        96

    st_conv1<<<1024, 256, 0, stream>>>(x, c1k, c1b, A);
    st_conv2<<<256, 256, 0, stream>>>(A, c2k, c2b, Bf);
    st_conv3<<<256, 256, 0, stream>>>(Bf, c3k, c3b, C3);
    st_pool3<<<1984, 256, 0, stream>>>(C3, gamma, beta, mean, var, xibuf, fprime);
    st_d1<<<dim3(64, 16), 256, 0, stream>>>(fprime, d1k, partial);
    st_d1b<<<4, 256, 0, stream>>>(partial, d1b, h1);
    st_theta<<<16, 128, 0, stream>>>(h1, d2k, d2b, d3k, d3b, theta);
    st_sample<<<131072, 256, 0, stream>>>(x, xibuf, theta, out);
}

// Round 2
// 309.360 us; speedup vs baseline: 1.1605x; 1.1605x over previous
//
#include <hip/hip_runtime.h>

// ---------------------------------------------------------------------------
// SpatialTransformer: conv1..3 (+relu+pool), BN+dense head -> theta,
// fused nearest-upsample+concat+bilinear-sampler+leaky-relu.
// All fp32. B=16, H=W=256, LOC_C=31.
// ---------------------------------------------------------------------------

#define NEG_SLOPE 0.1f
#define BN_EPS 1e-3f

// K1: conv1 (1->8, 3x3 SAME) + bias + relu + 2x2 maxpool.
// x:(16,256,256,1) -> A:(16,128,128,8). One thread per pooled pixel.
__global__ __launch_bounds__(256) void st_conv1(const float* __restrict__ x,
                                                const float* __restrict__ w,
                                                const float* __restrict__ bias,
                                                float* __restrict__ outA) {
    int idx = blockIdx.x * 256 + threadIdx.x;       // 16*128*128 = 262144
    int px = idx & 127, py = (idx >> 7) & 127, b = idx >> 14;
    const float* xb = x + b * 65536;
    int iy0 = 2 * py - 1, ix0 = 2 * px - 1;
    float p[16];
#pragma unroll
    for (int r = 0; r < 4; ++r) {
        int iy = iy0 + r;
        bool oky = (iy >= 0) && (iy < 256);
#pragma unroll
        for (int cc = 0; cc < 4; ++cc) {
            int ix = ix0 + cc;
            bool ok = oky && (ix >= 0) && (ix < 256);
            p[r * 4 + cc] = ok ? xb[iy * 256 + ix] : 0.0f;
        }
    }
    float m[8];
#pragma unroll
    for (int co = 0; co < 8; ++co) m[co] = -1e30f;
#pragma unroll
    for (int oy = 0; oy < 2; ++oy)
#pragma unroll
        for (int ox = 0; ox < 2; ++ox) {
            float acc[8];
#pragma unroll
            for (int co = 0; co < 8; ++co) acc[co] = 0.0f;
#pragma unroll
            for (int ky = 0; ky < 3; ++ky)
#pragma unroll
                for (int kx = 0; kx < 3; ++kx) {
                    float pv = p[(oy + ky) * 4 + (ox + kx)];
                    const float* wr = w + (ky * 3 + kx) * 8;
#pragma unroll
                    for (int co = 0; co < 8; ++co)
                        acc[co] = fmaf(pv, wr[co], acc[co]);
                }
#pragma unroll
            for (int co = 0; co < 8; ++co) m[co] = fmaxf(m[co], acc[co]);
        }
    float* o = outA + idx * 8;
#pragma unroll
    for (int co = 0; co < 8; ++co) {
        float v = m[co] + bias[co];
        o[co] = v > 0.0f ? v : 0.0f;
    }
}

// K2: conv2 (8->16) + bias + relu + pool. A:(16,128,128,8) -> Bf:(16,64,64,16)
// Split: 2 threads per pooled pixel (co halves) for occupancy.
__global__ __launch_bounds__(256) void st_conv2(const float* __restrict__ A,
                                                const float* __restrict__ w,
                                                const float* __restrict__ bias,
                                                float* __restrict__ outB) {
    int idx = blockIdx.x * 256 + threadIdx.x;       // 2*65536 = 131072
    int half = idx & 1;
    int pixel = idx >> 1;
    int px = pixel & 63, py = (pixel >> 6) & 63, b = pixel >> 12;
    const float* Ab = A + b * 128 * 128 * 8;
    int iy0 = 2 * py - 1, ix0 = 2 * px - 1;
    int cobase = half * 8;
    float acc[4][8];
#pragma unroll
    for (int pos = 0; pos < 4; ++pos)
#pragma unroll
        for (int co = 0; co < 8; ++co) acc[pos][co] = 0.0f;

    for (int ci = 0; ci < 8; ++ci) {
        float p[16];
#pragma unroll
        for (int r = 0; r < 4; ++r) {
            int iy = iy0 + r;
            bool oky = (iy >= 0) && (iy < 128);
#pragma unroll
            for (int cc = 0; cc < 4; ++cc) {
                int ix = ix0 + cc;
                bool ok = oky && (ix >= 0) && (ix < 128);
                p[r * 4 + cc] = ok ? Ab[(iy * 128 + ix) * 8 + ci] : 0.0f;
            }
        }
#pragma unroll
        for (int ky = 0; ky < 3; ++ky)
#pragma unroll
            for (int kx = 0; kx < 3; ++kx) {
                const float* wr = w + ((ky * 3 + kx) * 8 + ci) * 16 + cobase;
                float p00 = p[ky * 4 + kx];
                float p01 = p[ky * 4 + kx + 1];
                float p10 = p[(ky + 1) * 4 + kx];
                float p11 = p[(ky + 1) * 4 + kx + 1];
#pragma unroll
                for (int co = 0; co < 8; ++co) {
                    float wv = wr[co];
                    acc[0][co] = fmaf(p00, wv, acc[0][co]);
                    acc[1][co] = fmaf(p01, wv, acc[1][co]);
                    acc[2][co] = fmaf(p10, wv, acc[2][co]);
                    acc[3][co] = fmaf(p11, wv, acc[3][co]);
                }
            }
    }
    float* o = outB + pixel * 16 + cobase;
#pragma unroll
    for (int co = 0; co < 8; ++co) {
        float m = fmaxf(fmaxf(acc[0][co], acc[1][co]),
                        fmaxf(acc[2][co], acc[3][co]));
        m += bias[cobase + co];
        o[co] = m > 0.0f ? m : 0.0f;
    }
}

// K3: conv3 (16->31) + bias + relu (NO pool). Bf:(16,64,64,16) -> C3:(16,64,64,31)
// Split: 4 threads per pixel; groups cover co {0..7, 8..15, 16..23, 23..30}
// (last group overlaps 23 to stay in-bounds; duplicate write is identical).
__global__ __launch_bounds__(256) void st_conv3(const float* __restrict__ Bf,
                                                const float* __restrict__ w,
                                                const float* __restrict__ bias,
                                                float* __restrict__ outC) {
    int idx = blockIdx.x * 256 + threadIdx.x;       // 4*65536 = 262144
    int q = idx & 3;
    int pixel = idx >> 2;
    int ix = pixel & 63, iy = (pixel >> 6) & 63, b = pixel >> 12;
    int cobase = q * 8;
    if (cobase > 23) cobase = 23;
    const float* Bb = Bf + b * 64 * 64 * 16;
    float acc[8];
#pragma unroll
    for (int co = 0; co < 8; ++co) acc[co] = 0.0f;

    for (int ci = 0; ci < 16; ++ci) {
        float p[9];
#pragma unroll
        for (int ky = 0; ky < 3; ++ky) {
            int y = iy + ky - 1;
            bool oky = (y >= 0) && (y < 64);
#pragma unroll
            for (int kx = 0; kx < 3; ++kx) {
                int xx = ix + kx - 1;
                bool ok = oky && (xx >= 0) && (xx < 64);
                p[ky * 3 + kx] = ok ? Bb[(y * 64 + xx) * 16 + ci] : 0.0f;
            }
        }
#pragma unroll
        for (int k = 0; k < 9; ++k) {
            float pv = p[k];
            const float* wr = w + (k * 16 + ci) * 31 + cobase;
#pragma unroll
            for (int co = 0; co < 8; ++co)
                acc[co] = fmaf(pv, wr[co], acc[co]);
        }
    }
    float* o = outC + pixel * 31 + cobase;
#pragma unroll
    for (int co = 0; co < 8; ++co) {
        float v = acc[co] + bias[cobase + co];
        o[co] = v > 0.0f ? v : 0.0f;
    }
}

// K3b: 2x2 maxpool C3 -> xip (padded 32-ch cells, slot 0 unused) + BN'd fprime.
// xip layout: [b][cell=py*32+px][slot = 1+co], 32 floats/cell (128B aligned).
__global__ __launch_bounds__(256) void st_pool3(const float* __restrict__ C3,
                                                const float* __restrict__ gamma,
                                                const float* __restrict__ beta,
                                                const float* __restrict__ mean,
                                                const float* __restrict__ var,
                                                float* __restrict__ xip,
                                                float* __restrict__ fprime) {
    int idx = blockIdx.x * 256 + threadIdx.x;       // 16*31744 = 507904
    unsigned j = (unsigned)idx % 31744u;
    unsigned b = (unsigned)idx / 31744u;
    unsigned p2 = j / 31u;
    unsigned co = j - p2 * 31u;
    unsigned px = p2 & 31u, py = p2 >> 5;
    const float* Cb = C3 + b * 64 * 64 * 31;
    float m = -1e30f;
#pragma unroll
    for (int dy = 0; dy < 2; ++dy)
#pragma unroll
        for (int dx = 0; dx < 2; ++dx)
            m = fmaxf(m, Cb[((2 * py + dy) * 64 + (2 * px + dx)) * 31 + co]);
    xip[((b << 10) + p2) * 32 + 1 + co] = m;
    float sc = gamma[j] * rsqrtf(var[j] + BN_EPS);
    fprime[idx] = (m - mean[j]) * sc + beta[j];
}

// K4: split-K GEMM: partial[o][slice][b] = sum_{j in slice} fprime[b,j]*d1_k[j,o]
__global__ __launch_bounds__(256) void st_d1(const float* __restrict__ fp,
                                             const float* __restrict__ k1,
                                             float* __restrict__ partial) {
    int o = blockIdx.x;        // 64
    int slice = blockIdx.y;    // 16
    int t = threadIdx.x;
    float acc[16];
#pragma unroll
    for (int b = 0; b < 16; ++b) acc[b] = 0.0f;
    int jend = (slice + 1) * 1984;
    for (int j = slice * 1984 + t; j < jend; j += 256) {
        float kv = k1[j * 64 + o];
#pragma unroll
        for (int b = 0; b < 16; ++b)
            acc[b] = fmaf(fp[b * 31744 + j], kv, acc[b]);
    }
#pragma unroll
    for (int b = 0; b < 16; ++b) {
        float v = acc[b];
#pragma unroll
        for (int off = 32; off > 0; off >>= 1) v += __shfl_down(v, off, 64);
        acc[b] = v;
    }
    __shared__ float red[4][16];
    int wave = t >> 6, lane = t & 63;
    if (lane == 0) {
#pragma unroll
        for (int b = 0; b < 16; ++b) red[wave][b] = acc[b];
    }
    __syncthreads();
    if (t < 16) {
        float s = red[0][t] + red[1][t] + red[2][t] + red[3][t];
        partial[(o * 16 + slice) * 16 + t] = s;
    }
}

// K4b: reduce slices, add bias, relu -> h1 (16,64)
__global__ __launch_bounds__(256) void st_d1b(const float* __restrict__ partial,
                                              const float* __restrict__ bias,
                                              float* __restrict__ h1) {
    int gid = blockIdx.x * 256 + threadIdx.x;       // 1024
    int o = gid >> 4, b = gid & 15;
    float s = 0.0f;
#pragma unroll
    for (int sl = 0; sl < 16; ++sl) s += partial[(o * 16 + sl) * 16 + b];
    s += bias[o];
    h1[b * 64 + o] = s > 0.0f ? s : 0.0f;
}

// K5: d2 (64->96, relu) then d3 (96->6) -> theta (16,6). One block per batch.
__global__ __launch_bounds__(128) void st_theta(const float* __restrict__ h1,
                                                const float* __restrict__ k2,
                                                const float* __restrict__ b2,
                                                const float* __restrict__ k3,
                                                const float* __restrict__ b3,
                                                float* __restrict__ theta) {
    int b = blockIdx.x, t = threadIdx.x;
    __shared__ float h2[96];
    if (t < 96) {
        float s = b2[t];
        for (int i = 0; i < 64; ++i) s = fmaf(h1[b * 64 + i], k2[i * 96 + t], s);
        h2[t] = s > 0.0f ? s : 0.0f;
    }
    __syncthreads();
    if (t < 6) {
        float s = b3[t];
        for (int i = 0; i < 96; ++i) s = fmaf(h2[i], k3[i * 6 + t], s);
        theta[b * 6 + t] = s;
    }
}

// K6: fused grid-gen + nearest-upsample-concat + bilinear sampler + leaky relu.
// ONE THREAD PER PIXEL: grid math computed once, 32 channels via float4 chunk
// loads from padded cells. LDS-staged for fully coalesced output stores.
__global__ __launch_bounds__(256) void st_sample(const float* __restrict__ x,
                                                 const float* __restrict__ xip,
                                                 const float* __restrict__ theta,
                                                 float* __restrict__ out) {
    __shared__ float smem[256 * 33];                // stride 33: conflict-free
    int t = threadIdx.x;
    int p = blockIdx.x * 256 + t;                   // pixel id, 1,048,576 total
    int ow = p & 255, oh = (p >> 8) & 255;
    int b = blockIdx.x >> 8;                        // scalar: 256 blocks per batch

    const float* th = theta + b * 6;                // uniform -> s_load
    float t0 = th[0], t1 = th[1], t2 = th[2], t3 = th[3], t4 = th[4], t5 = th[5];
    float gx = (float)ow * (2.0f / 255.0f) - 1.0f;
    float gy = (float)oh * (2.0f / 255.0f) - 1.0f;
    float sx = gx * t0 + gy * t3 + t2;
    float sy = gx * t1 + gy * t4 + t5;
    float xf = 0.5f * ((sx + 1.0f) * 255.0f);
    float yf = 0.5f * ((sy + 1.0f) * 255.0f);
    float x0 = floorf(xf), y0 = floorf(yf);
    float x1 = x0 + 1.0f, y1 = y0 + 1.0f;
    x0 = fminf(fmaxf(x0, 0.0f), 255.0f);
    x1 = fminf(fmaxf(x1, 0.0f), 255.0f);
    y0 = fminf(fmaxf(y0, 0.0f), 255.0f);
    y1 = fminf(fmaxf(y1, 0.0f), 255.0f);
    float wa = (x1 - xf) * (y1 - yf);
    float wb = (x1 - xf) * (yf - y0);
    float wc = (xf - x0) * (y1 - yf);
    float wd = (xf - x0) * (yf - y0);
    int xi0 = (int)x0, xi1 = (int)x1, yi0 = (int)y0, yi1 = (int)y1;

    // fine sample (channel 0) from x
    const float* xb = x + b * 65536;
    float Ia = xb[yi0 * 256 + xi0];
    float Ib = xb[yi1 * 256 + xi0];
    float Ic = xb[yi0 * 256 + xi1];
    float Id = xb[yi1 * 256 + xi1];
    float fine = wa * Ia + wb * Ib + wc * Ic + wd * Id;
    fine = fine >= 0.0f ? fine : NEG_SLOPE * fine;

    // coarse cells (nearest-upsample == index>>3)
    const float* cellbase = xip + (b << 15);
    const float4* pa = (const float4*)(cellbase + (((yi0 >> 3) << 5) + (xi0 >> 3)) * 32);
    const float4* pb = (const float4*)(cellbase + (((yi1 >> 3) << 5) + (xi0 >> 3)) * 32);
    const float4* pc = (const float4*)(cellbase + (((yi0 >> 3) << 5) + (xi1 >> 3)) * 32);
    const float4* pd = (const float4*)(cellbase + (((yi1 >> 3) << 5) + (xi1 >> 3)) * 32);

    int sbase = t * 33;
#pragma unroll
    for (int k = 0; k < 8; ++k) {
        float4 va = pa[k], vb = pb[k], vc = pc[k], vd = pd[k];
        float vx = fmaf(wa, va.x, fmaf(wb, vb.x, fmaf(wc, vc.x, wd * vd.x)));
        float vy = fmaf(wa, va.y, fmaf(wb, vb.y, fmaf(wc, vc.y, wd * vd.y)));
        float vz = fmaf(wa, va.z, fmaf(wb, vb.z, fmaf(wc, vc.z, wd * vd.z)));
        float vw = fmaf(wa, va.w, fmaf(wb, vb.w, fmaf(wc, vc.w, wd * vd.w)));
        vx = vx >= 0.0f ? vx : NEG_SLOPE * vx;
        vy = vy >= 0.0f ? vy : NEG_SLOPE * vy;
        vz = vz >= 0.0f ? vz : NEG_SLOPE * vz;
        vw = vw >= 0.0f ? vw : NEG_SLOPE * vw;
        if (k == 0) vx = fine;                      // slot 0 = fine x channel
        smem[sbase + 4 * k]     = vx;
        smem[sbase + 4 * k + 1] = vy;
        smem[sbase + 4 * k + 2] = vz;
        smem[sbase + 4 * k + 3] = vw;
    }
    __syncthreads();

    // coalesced writeback: block covers out[blockIdx*8192 .. +8192)
    float* ob = out + blockIdx.x * 8192;
#pragma unroll
    for (int i = 0; i < 32; ++i) {
        int idx = i * 256 + t;
        ob[idx] = smem[(idx >> 5) * 33 + (idx & 31)];
    }
}

extern "C" void kernel_launch(void* const* d_in, const int* in_sizes, int n_in,
                              void* d_out, int out_size, void* d_ws, size_t ws_size,
                              hipStream_t stream) {
    const float* x     = (const float*)d_in[0];
    const float* c1k   = (const float*)d_in[1];
    const float* c1b   = (const float*)d_in[2];
    const float* c2k   = (const float*)d_in[3];
    const float* c2b   = (const float*)d_in[4];
    const float* c3k   = (const float*)d_in[5];
    const float* c3b   = (const float*)d_in[6];
    const float* gamma = (const float*)d_in[7];
    const float* beta  = (const float*)d_in[8];
    const float* mean  = (const float*)d_in[9];
    const float* var   = (const float*)d_in[10];
    const float* d1k   = (const float*)d_in[11];
    const float* d1b   = (const float*)d_in[12];
    const float* d2k   = (const float*)d_in[13];
    const float* d2b   = (const float*)d_in[14];
    const float* d3k   = (const float*)d_in[15];
    const float* d3b   = (const float*)d_in[16];
    float* out = (float*)d_out;
    float* ws  = (float*)d_ws;

    // Workspace layout (floats). Region reuse: C3 overwrites A (A dead after
    // conv2); xip+fprime overwrite Bf (Bf dead after conv3).
    float* A       = ws;                            // 2,097,152
    float* Bf      = ws + 2097152;                  // 1,048,576
    float* C3      = ws;                            // 2,031,616 (reuse A)
    float* xip     = ws + 2097152;                  //   524,288 (reuse Bf)
    float* fprime  = ws + 2097152 + 524288;         //   507,904
    float* partial = ws + 3145728;                  //    16,384
    float* h1      = ws + 3145728 + 16384;          //     1,024
    float* theta   = ws + 3145728 + 17408;          //        96

    st_conv1<<<1024, 256, 0, stream>>>(x, c1k, c1b, A);
    st_conv2<<<512, 256, 0, stream>>>(A, c2k, c2b, Bf);
    st_conv3<<<1024, 256, 0, stream>>>(Bf, c3k, c3b, C3);
    st_pool3<<<1984, 256, 0, stream>>>(C3, gamma, beta, mean, var, xip, fprime);
    st_d1<<<dim3(64, 16), 256, 0, stream>>>(fprime, d1k, partial);
    st_d1b<<<4, 256, 0, stream>>>(partial, d1b, h1);
    st_theta<<<16, 128, 0, stream>>>(h1, d2k, d2b, d3k, d3b, theta);
    st_sample<<<4096, 256, 0, stream>>>(x, xip, theta, out);
}

// Round 4
// 279.380 us; speedup vs baseline: 1.2851x; 1.1073x over previous
//
#include <hip/hip_runtime.h>

// ---------------------------------------------------------------------------
// SpatialTransformer: conv1..3 (+relu+pool), BN+dense head -> theta,
// fused nearest-upsample+concat+bilinear-sampler+leaky-relu.
// All fp32. B=16, H=W=256, LOC_C=31.
// Key idioms: wave-uniform co-groups -> weight loads are s_load (SGPR
// broadcast, no per-lane VMEM); float4 input loads; padded 32-ch layouts.
// ---------------------------------------------------------------------------

#define NEG_SLOPE 0.1f
#define BN_EPS 1e-3f

typedef float vfloat4 __attribute__((ext_vector_type(4)));  // native vector for
                                                            // nontemporal stores

__device__ __forceinline__ void fma8(float pv, const float* __restrict__ wk,
                                     float* __restrict__ acc) {
#pragma unroll
    for (int co = 0; co < 8; ++co) acc[co] = fmaf(pv, wk[co], acc[co]);
}

// K1: conv1 (1->8, 3x3 SAME) + bias + relu + 2x2 maxpool.
// x:(16,256,256,1) -> A:(16,128,128,8). One thread per pooled pixel.
// Weights are thread-uniform -> compiler scalarizes them already.
__global__ __launch_bounds__(256, 4) void st_conv1(const float* __restrict__ x,
                                                   const float* __restrict__ w,
                                                   const float* __restrict__ bias,
                                                   float* __restrict__ outA) {
    int idx = blockIdx.x * 256 + threadIdx.x;       // 262144
    int px = idx & 127, py = (idx >> 7) & 127, b = idx >> 14;
    const float* xb = x + b * 65536;
    int iy0 = 2 * py - 1, ix0 = 2 * px - 1;
    float p[16];
#pragma unroll
    for (int r = 0; r < 4; ++r) {
        int iy = iy0 + r;
        bool oky = (iy >= 0) && (iy < 256);
#pragma unroll
        for (int cc = 0; cc < 4; ++cc) {
            int ix = ix0 + cc;
            bool ok = oky && (ix >= 0) && (ix < 256);
            p[r * 4 + cc] = ok ? xb[iy * 256 + ix] : 0.0f;
        }
    }
    float m[8];
#pragma unroll
    for (int co = 0; co < 8; ++co) m[co] = -1e30f;
#pragma unroll
    for (int oy = 0; oy < 2; ++oy)
#pragma unroll
        for (int ox = 0; ox < 2; ++ox) {
            float acc[8];
#pragma unroll
            for (int co = 0; co < 8; ++co) acc[co] = 0.0f;
#pragma unroll
            for (int ky = 0; ky < 3; ++ky)
#pragma unroll
                for (int kx = 0; kx < 3; ++kx)
                    fma8(p[(oy + ky) * 4 + (ox + kx)], w + (ky * 3 + kx) * 8, acc);
#pragma unroll
            for (int co = 0; co < 8; ++co) m[co] = fmaxf(m[co], acc[co]);
        }
    float4 o0, o1;
    float r0 = m[0] + bias[0], r1 = m[1] + bias[1], r2 = m[2] + bias[2], r3 = m[3] + bias[3];
    float r4 = m[4] + bias[4], r5 = m[5] + bias[5], r6 = m[6] + bias[6], r7 = m[7] + bias[7];
    o0.x = r0 > 0.f ? r0 : 0.f; o0.y = r1 > 0.f ? r1 : 0.f;
    o0.z = r2 > 0.f ? r2 : 0.f; o0.w = r3 > 0.f ? r3 : 0.f;
    o1.x = r4 > 0.f ? r4 : 0.f; o1.y = r5 > 0.f ? r5 : 0.f;
    o1.z = r6 > 0.f ? r6 : 0.f; o1.w = r7 > 0.f ? r7 : 0.f;
    *(float4*)(outA + idx * 8) = o0;
    *(float4*)(outA + idx * 8 + 4) = o1;
}

// K2: conv2 (8->16) + bias + relu + pool. A:(16,128,128,8) -> Bf:(16,64,64,16)
// Wave-uniform co-half; float4 input loads; scalar (SGPR) weight loads.
__global__ __launch_bounds__(256, 2) void st_conv2(const float* __restrict__ A,
                                                   const float* __restrict__ w,
                                                   const float* __restrict__ bias,
                                                   float* __restrict__ outB) {
    int t = threadIdx.x;
    int lane = t & 63;
    int half = __builtin_amdgcn_readfirstlane((t >> 6) & 1);   // wave-uniform
    int pixel = blockIdx.x * 128 + ((t >> 7) << 6) + lane;     // 65536 pooled px
    int px = pixel & 63, py = (pixel >> 6) & 63, b = pixel >> 12;
    const float* Ab = A + b * 128 * 128 * 8;
    int iy0 = 2 * py - 1, ix0 = 2 * px - 1;
    int cobase = half * 8;                                      // scalar
    float acc[4][8];
#pragma unroll
    for (int pos = 0; pos < 4; ++pos)
#pragma unroll
        for (int co = 0; co < 8; ++co) acc[pos][co] = 0.0f;

    const float4 z4 = {0.f, 0.f, 0.f, 0.f};
#pragma unroll
    for (int ciq = 0; ciq < 2; ++ciq) {
        float4 p[16];
#pragma unroll
        for (int r = 0; r < 4; ++r) {
            int iy = iy0 + r;
            bool oky = (iy >= 0) && (iy < 128);
#pragma unroll
            for (int cc = 0; cc < 4; ++cc) {
                int ix = ix0 + cc;
                bool ok = oky && (ix >= 0) && (ix < 128);
                p[r * 4 + cc] = ok ? *(const float4*)(Ab + ((iy * 128 + ix) * 8 + ciq * 4))
                                   : z4;
            }
        }
#pragma unroll
        for (int oy = 0; oy < 2; ++oy)
#pragma unroll
            for (int ox = 0; ox < 2; ++ox)
#pragma unroll
                for (int ky = 0; ky < 3; ++ky)
#pragma unroll
                    for (int kx = 0; kx < 3; ++kx) {
                        float4 pv = p[(oy + ky) * 4 + (ox + kx)];
                        const float* wk = w + ((ky * 3 + kx) * 8 + ciq * 4) * 16 + cobase;
                        float* a = acc[oy * 2 + ox];
                        fma8(pv.x, wk, a);
                        fma8(pv.y, wk + 16, a);
                        fma8(pv.z, wk + 32, a);
                        fma8(pv.w, wk + 48, a);
                    }
    }
    float* o = outB + pixel * 16 + cobase;
#pragma unroll
    for (int co = 0; co < 8; ++co) {
        float m = fmaxf(fmaxf(acc[0][co], acc[1][co]),
                        fmaxf(acc[2][co], acc[3][co]));
        m += bias[cobase + co];
        o[co] = m > 0.0f ? m : 0.0f;
    }
}

// K3: conv3 (16->31) + bias + relu. Bf:(16,64,64,16) -> C3p padded stride 32.
// Wave-uniform co-octet {0,8,16,23}; float4 input loads; SGPR weights.
__global__ __launch_bounds__(256, 4) void st_conv3(const float* __restrict__ Bf,
                                                   const float* __restrict__ w,
                                                   const float* __restrict__ bias,
                                                   float* __restrict__ outC) {
    int t = threadIdx.x;
    int lane = t & 63;
    int q = __builtin_amdgcn_readfirstlane(t >> 6);            // wave-uniform
    int cobase = q * 8;
    if (cobase > 23) cobase = 23;
    int pixel = blockIdx.x * 64 + lane;                        // 65536 pixels
    int ix = pixel & 63, iy = (pixel >> 6) & 63, b = pixel >> 12;
    const float* Bb = Bf + b * 64 * 64 * 16;
    float acc[8];
#pragma unroll
    for (int co = 0; co < 8; ++co) acc[co] = 0.0f;

    const float4 z4 = {0.f, 0.f, 0.f, 0.f};
#pragma unroll
    for (int ciq = 0; ciq < 4; ++ciq) {
        float4 p[9];
#pragma unroll
        for (int ky = 0; ky < 3; ++ky) {
            int y = iy + ky - 1;
            bool oky = (y >= 0) && (y < 64);
#pragma unroll
            for (int kx = 0; kx < 3; ++kx) {
                int xx = ix + kx - 1;
                bool ok = oky && (xx >= 0) && (xx < 64);
                p[ky * 3 + kx] = ok ? *(const float4*)(Bb + ((y * 64 + xx) * 16 + ciq * 4))
                                    : z4;
            }
        }
#pragma unroll
        for (int k = 0; k < 9; ++k) {
            float4 pv = p[k];
            const float* wk = w + (k * 16 + ciq * 4) * 31 + cobase;
            fma8(pv.x, wk, acc);
            fma8(pv.y, wk + 31, acc);
            fma8(pv.z, wk + 62, acc);
            fma8(pv.w, wk + 93, acc);
        }
    }
    float* o = outC + pixel * 32 + cobase;                     // stride-32 padded
#pragma unroll
    for (int co = 0; co < 8; ++co) {
        float v = acc[co] + bias[cobase + co];
        o[co] = v > 0.0f ? v : 0.0f;
    }
}

// K3b: 2x2 maxpool C3p -> xip (stride-32 cells, slot=co) + BN'd fprime.
// Thread per (pooled pixel, channel-quad). All 16B loads/stores.
// Note: quad 7 component 3 reads C3p slot 31 = poison (finite) -> xip slot 31,
// which st_sample routes to a dead LDS pad column.
__global__ __launch_bounds__(256) void st_pool3(const float* __restrict__ C3p,
                                                const float* __restrict__ gamma,
                                                const float* __restrict__ beta,
                                                const float* __restrict__ mean,
                                                const float* __restrict__ var,
                                                float* __restrict__ xip,
                                                float* __restrict__ fprime) {
    int idx = blockIdx.x * 256 + threadIdx.x;      // 131072
    int quad = idx & 7;
    int pp = idx >> 3;                             // pooled pixel 0..16383
    int b = pp >> 10;
    int cell = pp & 1023;
    int py = cell >> 5, px = cell & 31;
    const float* Cb = C3p + (b * 4096) * 32 + quad * 4;
    float4 v00 = *(const float4*)(Cb + ((2 * py) * 64 + 2 * px) * 32);
    float4 v01 = *(const float4*)(Cb + ((2 * py) * 64 + 2 * px + 1) * 32);
    float4 v10 = *(const float4*)(Cb + ((2 * py + 1) * 64 + 2 * px) * 32);
    float4 v11 = *(const float4*)(Cb + ((2 * py + 1) * 64 + 2 * px + 1) * 32);
    float4 m;
    m.x = fmaxf(fmaxf(v00.x, v01.x), fmaxf(v10.x, v11.x));
    m.y = fmaxf(fmaxf(v00.y, v01.y), fmaxf(v10.y, v11.y));
    m.z = fmaxf(fmaxf(v00.z, v01.z), fmaxf(v10.z, v11.z));
    m.w = fmaxf(fmaxf(v00.w, v01.w), fmaxf(v10.w, v11.w));
    *(float4*)(xip + (b * 1024 + cell) * 32 + quad * 4) = m;
    int c0 = quad * 4;
    float mv[4] = {m.x, m.y, m.z, m.w};
#pragma unroll
    for (int c = 0; c < 4; ++c) {
        int co = c0 + c;
        if (co < 31) {
            int j = cell * 31 + co;
            float sc = gamma[j] * rsqrtf(var[j] + BN_EPS);
            fprime[b * 31744 + j] = (mv[c] - mean[j]) * sc + beta[j];
        }
    }
}

// K4: split-K GEMM d1. lane=o -> coalesced k1 reads; wave-uniform j -> SGPR
// fp reads. partial[(s*64+o)*16+b].
__global__ __launch_bounds__(256) void st_d1(const float* __restrict__ fp,
                                             const float* __restrict__ k1,
                                             float* __restrict__ partial) {
    int t = threadIdx.x, s = blockIdx.x;           // 256 slices of 124 j's
    int o = t & 63;
    int sub = t >> 6;
    int subu = __builtin_amdgcn_readfirstlane(sub);
    int j0 = s * 124 + subu * 31;
    float acc[16];
#pragma unroll
    for (int b = 0; b < 16; ++b) acc[b] = 0.0f;
#pragma unroll 4
    for (int jj = 0; jj < 31; ++jj) {
        int j = j0 + jj;
        float kv = k1[j * 64 + o];                 // coalesced
        const float* fpj = fp + j;                 // scalar base
#pragma unroll
        for (int b = 0; b < 16; ++b)
            acc[b] = fmaf(fpj[b * 31744], kv, acc[b]);   // s_load operand
    }
    __shared__ float red[4][16][64];
#pragma unroll
    for (int b = 0; b < 16; ++b) red[sub][b][o] = acc[b];
    __syncthreads();
    if (sub == 0) {
#pragma unroll
        for (int b = 0; b < 16; ++b) {
            float v = red[0][b][o] + red[1][b][o] + red[2][b][o] + red[3][b][o];
            partial[(s * 64 + o) * 16 + b] = v;
        }
    }
}

// K4b: reduce slices, add bias, relu -> h1 (16,64)
__global__ __launch_bounds__(256) void st_d1b(const float* __restrict__ partial,
                                              const float* __restrict__ bias,
                                              float* __restrict__ h1) {
    int gid = blockIdx.x * 256 + threadIdx.x;      // 1024
    int o = gid >> 4, b = gid & 15;
    float s = 0.0f;
#pragma unroll 8
    for (int sl = 0; sl < 256; ++sl) s += partial[(sl * 64 + o) * 16 + b];
    s += bias[o];
    h1[b * 64 + o] = s > 0.0f ? s : 0.0f;
}

// K5: d2 (64->96, relu) then d3 (96->6) -> theta (16,6). One block per batch.
__global__ __launch_bounds__(128) void st_theta(const float* __restrict__ h1,
                                                const float* __restrict__ k2,
                                                const float* __restrict__ b2,
                                                const float* __restrict__ k3,
                                                const float* __restrict__ b3,
                                                float* __restrict__ theta) {
    int b = blockIdx.x, t = threadIdx.x;
    __shared__ float h2[96];
    if (t < 96) {
        float s = b2[t];
        for (int i = 0; i < 64; ++i) s = fmaf(h1[b * 64 + i], k2[i * 96 + t], s);
        h2[t] = s > 0.0f ? s : 0.0f;
    }
    __syncthreads();
    if (t < 6) {
        float s = b3[t];
        for (int i = 0; i < 96; ++i) s = fmaf(h2[i], k3[i * 6 + t], s);
        theta[b * 6 + t] = s;
    }
}

// K6: fused grid-gen + upsample-concat + bilinear sampler + leaky relu.
// One thread per pixel; stride-34 LDS (2-way conflicts = free; rows 8B
// aligned for ds_read_b64); nontemporal native-vector stores.
__global__ __launch_bounds__(256, 4) void st_sample(const float* __restrict__ x,
                                                    const float* __restrict__ xip,
                                                    const float* __restrict__ theta,
                                                    float* __restrict__ out) {
    __shared__ float smem[256 * 34];
    int t = threadIdx.x;
    int p = blockIdx.x * 256 + t;                  // 1,048,576 pixels
    int ow = p & 255, oh = (p >> 8) & 255;
    int b = blockIdx.x >> 8;                       // 256 blocks per batch

    const float* th = theta + b * 6;               // uniform -> s_load
    float t0 = th[0], t1 = th[1], t2 = th[2], t3 = th[3], t4 = th[4], t5 = th[5];
    float gx = (float)ow * (2.0f / 255.0f) - 1.0f;
    float gy = (float)oh * (2.0f / 255.0f) - 1.0f;
    float sx = gx * t0 + gy * t3 + t2;
    float sy = gx * t1 + gy * t4 + t5;
    float xf = 0.5f * ((sx + 1.0f) * 255.0f);
    float yf = 0.5f * ((sy + 1.0f) * 255.0f);
    float x0 = floorf(xf), y0 = floorf(yf);
    float x1 = x0 + 1.0f, y1 = y0 + 1.0f;
    x0 = fminf(fmaxf(x0, 0.0f), 255.0f);
    x1 = fminf(fmaxf(x1, 0.0f), 255.0f);
    y0 = fminf(fmaxf(y0, 0.0f), 255.0f);
    y1 = fminf(fmaxf(y1, 0.0f), 255.0f);
    float wa = (x1 - xf) * (y1 - yf);
    float wb = (x1 - xf) * (yf - y0);
    float wc = (xf - x0) * (y1 - yf);
    float wd = (xf - x0) * (yf - y0);
    int xi0 = (int)x0, xi1 = (int)x1, yi0 = (int)y0, yi1 = (int)y1;

    const float* xb = x + b * 65536;
    float Ia = xb[yi0 * 256 + xi0];
    float Ib = xb[yi1 * 256 + xi0];
    float Ic = xb[yi0 * 256 + xi1];
    float Id = xb[yi1 * 256 + xi1];
    float fine = wa * Ia + wb * Ib + wc * Ic + wd * Id;
    fine = fine >= 0.0f ? fine : NEG_SLOPE * fine;

    const float* cellbase = xip + (b << 15);
    const float4* pa = (const float4*)(cellbase + (((yi0 >> 3) << 5) + (xi0 >> 3)) * 32);
    const float4* pb = (const float4*)(cellbase + (((yi1 >> 3) << 5) + (xi0 >> 3)) * 32);
    const float4* pc = (const float4*)(cellbase + (((yi0 >> 3) << 5) + (xi1 >> 3)) * 32);
    const float4* pd = (const float4*)(cellbase + (((yi1 >> 3) << 5) + (xi1 >> 3)) * 32);

    int sbase = t * 34;
    smem[sbase] = fine;                            // out channel 0
#pragma unroll
    for (int k = 0; k < 8; ++k) {
        float4 va = pa[k], vb = pb[k], vc = pc[k], vd = pd[k];
        float vx = fmaf(wa, va.x, fmaf(wb, vb.x, fmaf(wc, vc.x, wd * vd.x)));
        float vy = fmaf(wa, va.y, fmaf(wb, vb.y, fmaf(wc, vc.y, wd * vd.y)));
        float vz = fmaf(wa, va.z, fmaf(wb, vb.z, fmaf(wc, vc.z, wd * vd.z)));
        float vw = fmaf(wa, va.w, fmaf(wb, vb.w, fmaf(wc, vc.w, wd * vd.w)));
        vx = vx >= 0.0f ? vx : NEG_SLOPE * vx;
        vy = vy >= 0.0f ? vy : NEG_SLOPE * vy;
        vz = vz >= 0.0f ? vz : NEG_SLOPE * vz;
        vw = vw >= 0.0f ? vw : NEG_SLOPE * vw;
        // out channel = 1 + co; k=7 comp w (co=31, garbage) -> col 32 = pad
        smem[sbase + 1 + 4 * k]     = vx;
        smem[sbase + 2 + 4 * k]     = vy;
        smem[sbase + 3 + 4 * k]     = vz;
        smem[sbase + 4 + 4 * k]     = vw;
    }
    __syncthreads();

    vfloat4* ob = (vfloat4*)(out + blockIdx.x * 8192);
#pragma unroll
    for (int i = 0; i < 8; ++i) {
        int g = i * 256 + t;                       // float4 index 0..2047
        int row = g >> 3, col = 4 * (g & 7);
        float2 lo = *(const float2*)&smem[row * 34 + col];
        float2 hi = *(const float2*)&smem[row * 34 + col + 2];
        vfloat4 v = {lo.x, lo.y, hi.x, hi.y};
        __builtin_nontemporal_store(v, ob + g);
    }
}

extern "C" void kernel_launch(void* const* d_in, const int* in_sizes, int n_in,
                              void* d_out, int out_size, void* d_ws, size_t ws_size,
                              hipStream_t stream) {
    const float* x     = (const float*)d_in[0];
    const float* c1k   = (const float*)d_in[1];
    const float* c1b   = (const float*)d_in[2];
    const float* c2k   = (const float*)d_in[3];
    const float* c2b   = (const float*)d_in[4];
    const float* c3k   = (const float*)d_in[5];
    const float* c3b   = (const float*)d_in[6];
    const float* gamma = (const float*)d_in[7];
    const float* beta  = (const float*)d_in[8];
    const float* mean  = (const float*)d_in[9];
    const float* var   = (const float*)d_in[10];
    const float* d1k   = (const float*)d_in[11];
    const float* d1b   = (const float*)d_in[12];
    const float* d2k   = (const float*)d_in[13];
    const float* d2b   = (const float*)d_in[14];
    const float* d3k   = (const float*)d_in[15];
    const float* d3b   = (const float*)d_in[16];
    float* out = (float*)d_out;
    float* ws  = (float*)d_ws;

    // Workspace (floats). C3p reuses A (A dead after conv2); xip reuses Bf.
    float* A       = ws;                           // [0, 2097152)
    float* Bf      = ws + 2097152;                 // [2097152, 3145728)
    float* C3p     = ws;                           // 65536*32 = 2097152 (=A)
    float* xip     = ws + 2097152;                 // 16384*32 = 524288 (=Bf)
    float* fprime  = ws + 3145728;                 // 507904
    float* partial = ws + 3653632;                 // 262144
    float* h1      = ws + 3915776;                 // 1024
    float* theta   = ws + 3916800;                 // 96

    st_conv1<<<1024, 256, 0, stream>>>(x, c1k, c1b, A);
    st_conv2<<<512, 256, 0, stream>>>(A, c2k, c2b, Bf);
    st_conv3<<<1024, 256, 0, stream>>>(Bf, c3k, c3b, C3p);
    st_pool3<<<512, 256, 0, stream>>>(C3p, gamma, beta, mean, var, xip, fprime);
    st_d1<<<256, 256, 0, stream>>>(fprime, d1k, partial);
    st_d1b<<<4, 256, 0, stream>>>(partial, d1b, h1);
    st_theta<<<16, 128, 0, stream>>>(h1, d2k, d2b, d3k, d3b, theta);
    st_sample<<<4096, 256, 0, stream>>>(x, xip, theta, out);
}